// Round 6
// baseline (240.828 us; speedup 1.0000x reference)
//
#include <hip/hip_runtime.h>

#define DM 1024
#define NW 16384

typedef __attribute__((ext_vector_type(8))) short short8;
typedef __attribute__((ext_vector_type(4))) float f32x4;

// ws layout (float offsets)
#define OFF_AH   1024       // A-frag hi: 16384 shorts = 8192 floats
#define OFF_AL   9216       // A-frag lo: 16384 shorts
#define OFF_D0   17408      // 16
#define OFF_S    17424      // 16 heads, stride 16 floats = 256
#define OFF_X    17696      // 1024
#define OFF_W    18720      // 16*1024
#define OFF_E    36864      // e[NW][16] = 262144
#define OFF_PART 299008     // partials [64][16][1024] = 1048576

// fp32 -> bf16 round-to-nearest-even (returns bits)
__device__ __forceinline__ unsigned short f2bf(float f) {
  unsigned int u = __float_as_uint(f);
  return (unsigned short)((u + 0x7fffu + ((u >> 16) & 1u)) >> 16);
}

// out[r] = dot(W[r,:], v) + b[r]   — one wave per row, 1024 waves
__global__ __launch_bounds__(256) void k_rowdot(const float* __restrict__ W,
                                                const float* __restrict__ v,
                                                const float* __restrict__ b,
                                                float* __restrict__ out) {
  const int wave = (blockIdx.x * 256 + threadIdx.x) >> 6;
  const int lane = threadIdx.x & 63;
  const float* row = W + (size_t)wave * DM + 4 * lane;
  float s = 0.f;
#pragma unroll
  for (int j = 0; j < 4; ++j) {
    float4 a = *(const float4*)(row + j * 256);
    float4 x = *(const float4*)(v + j * 256 + 4 * lane);
    s += a.x * x.x + a.y * x.y + a.z * x.z + a.w * x.w;
  }
#pragma unroll
  for (int off = 32; off; off >>= 1) s += __shfl_xor(s, off, 64);
  if (lane == 0) out[wave] = s + b[wave];
}

// Fused: q_h = query@Wq_h^T + bq (LDS), then c[h,m] = q_h · Wk[h*64+:,m],
// emitted directly as MFMA A-fragments (bf16 hi+lo, layout [kb][q*16+h][j]).
// d0[h] = q_h · bk_h. Also zeroes S.
__global__ __launch_bounds__(256) void k_qck(const float* __restrict__ Wq,
                                             const float* __restrict__ bq,
                                             const float* __restrict__ query,
                                             const float* __restrict__ Wk,
                                             const float* __restrict__ bk,
                                             short* __restrict__ Ah,
                                             short* __restrict__ Al,
                                             float* __restrict__ d0,
                                             float* __restrict__ S) {
  const int h = blockIdx.x >> 2;
  const int mc = blockIdx.x & 3;
  const int t = threadIdx.x;
  const int lane = t & 63;
  const int wv = t >> 6;
  __shared__ float qh[64];
  if (blockIdx.x == 0 && t < 16) S[t * 16] = 0.f;
  float4 qv[4];
#pragma unroll
  for (int j = 0; j < 4; ++j) qv[j] = *(const float4*)(query + j * 256 + 4 * lane);
#pragma unroll 1
  for (int i = 0; i < 16; i += 2) {
    const int d0i = 4 * i + wv;
    const int d1i = 4 * (i + 1) + wv;
    const float* r0 = Wq + (size_t)(h * 64 + d0i) * DM + 4 * lane;
    const float* r1 = Wq + (size_t)(h * 64 + d1i) * DM + 4 * lane;
    float4 a0[4], a1[4];
#pragma unroll
    for (int j = 0; j < 4; ++j) { a0[j] = *(const float4*)(r0 + j * 256);
                                  a1[j] = *(const float4*)(r1 + j * 256); }
    float s0 = 0.f, s1 = 0.f;
#pragma unroll
    for (int j = 0; j < 4; ++j) {
      s0 += a0[j].x * qv[j].x + a0[j].y * qv[j].y + a0[j].z * qv[j].z + a0[j].w * qv[j].w;
      s1 += a1[j].x * qv[j].x + a1[j].y * qv[j].y + a1[j].z * qv[j].z + a1[j].w * qv[j].w;
    }
#pragma unroll
    for (int off = 32; off; off >>= 1) { s0 += __shfl_xor(s0, off, 64);
                                         s1 += __shfl_xor(s1, off, 64); }
    if (lane == 0) { qh[d0i] = s0 + bq[h * 64 + d0i];
                     qh[d1i] = s1 + bq[h * 64 + d1i]; }
  }
  __syncthreads();
  // c for (h, m) then split to bf16 hi/lo in A-fragment layout
  const int m = mc * 256 + t;
  const float* Wp = Wk + (size_t)(h * 64) * DM + m;
  float s = 0.f;
#pragma unroll 1
  for (int db = 0; db < 8; ++db) {
    float wv8[8];
#pragma unroll
    for (int j = 0; j < 8; ++j) wv8[j] = Wp[(size_t)(db * 8 + j) * DM];
#pragma unroll
    for (int j = 0; j < 8; ++j) s = fmaf(qh[db * 8 + j], wv8[j], s);
  }
  unsigned short hu = f2bf(s);
  float hf = __uint_as_float(((unsigned int)hu) << 16);
  unsigned short lu = f2bf(s - hf);
  const int kb = m >> 5, q = (m >> 3) & 3, j = m & 7;
  const int idx = (kb * 64 + q * 16 + h) * 8 + j;
  Ah[idx] = (short)hu;
  Al[idx] = (short)lu;
  if (mc == 0 && t == 0) {
    float tt = 0.f;
    for (int d = 0; d < 64; ++d) tt += qh[d] * bk[h * 64 + d];
    d0[h] = tt;
  }
}

// MFMA scores: e[n][h] = exp(score + d0[h]); S[h*16] += partial sums.
// Tile = 16 heads x 16 rows; wave per tile; K=1024 via 32x mfma_16x16x32_bf16
// with hi/lo split (3 mfma/K-block) for fp32-grade accuracy. A frags in LDS.
__global__ __launch_bounds__(256) void k_scores(const float* __restrict__ key,
                                                const short* __restrict__ AhG,
                                                const short* __restrict__ AlG,
                                                const float* __restrict__ d0,
                                                float* __restrict__ e,
                                                float* __restrict__ S) {
  __shared__ short Ahi[16384];   // [kb*64 + lane][8] bf16 hi
  __shared__ short Alo[16384];
  const int t = threadIdx.x;
  const int lane = t & 63;
  const int wv = t >> 6;
  // stage A fragments: 64 KB from global (L3-hot, same for all blocks)
#pragma unroll
  for (int i = 0; i < 8; ++i) {
    *(short8*)&Ahi[(t + i * 256) * 8] = *(const short8*)&AhG[(t + i * 256) * 8];
    *(short8*)&Alo[(t + i * 256) * 8] = *(const short8*)&AlG[(t + i * 256) * 8];
  }
  __syncthreads();

  const int tile = blockIdx.x * 4 + wv;           // 0..1023
  const int n = tile * 16 + (lane & 15);
  const int quad = lane >> 4;
  const float* base = key + (size_t)n * DM + quad * 8;

  f32x4 acc = {0.f, 0.f, 0.f, 0.f};
  float4 f0[4], f1[4];
#pragma unroll
  for (int p = 0; p < 4; ++p) {
    f0[p] = *(const float4*)(base + p * 32);
    f1[p] = *(const float4*)(base + p * 32 + 4);
  }
#pragma unroll
  for (int kb = 0; kb < 32; ++kb) {
    const int slot = kb & 3;
    float4 a0 = f0[slot], a1 = f1[slot];
    if (kb < 28) {
      f0[slot] = *(const float4*)(base + (kb + 4) * 32);
      f1[slot] = *(const float4*)(base + (kb + 4) * 32 + 4);
    }
    short8 ah = *(const short8*)&Ahi[(kb * 64 + lane) * 8];
    short8 al = *(const short8*)&Alo[(kb * 64 + lane) * 8];
    float ff[8] = {a0.x, a0.y, a0.z, a0.w, a1.x, a1.y, a1.z, a1.w};
    short8 bh, bl;
#pragma unroll
    for (int j = 0; j < 8; ++j) {
      unsigned short hu = f2bf(ff[j]);
      bh[j] = (short)hu;
      float hf = __uint_as_float(((unsigned int)hu) << 16);
      bl[j] = (short)f2bf(ff[j] - hf);
    }
    acc = __builtin_amdgcn_mfma_f32_16x16x32_bf16(ah, bh, acc, 0, 0, 0);
    acc = __builtin_amdgcn_mfma_f32_16x16x32_bf16(ah, bl, acc, 0, 0, 0);
    acc = __builtin_amdgcn_mfma_f32_16x16x32_bf16(al, bh, acc, 0, 0, 0);
  }
  // epilogue: add d0, exp, store e, accumulate S
  const float4 dv = *(const float4*)(d0 + quad * 4);
  float ex0 = __expf(acc[0] + dv.x);
  float ex1 = __expf(acc[1] + dv.y);
  float ex2 = __expf(acc[2] + dv.z);
  float ex3 = __expf(acc[3] + dv.w);
  *(float4*)(e + (size_t)n * 16 + quad * 4) = make_float4(ex0, ex1, ex2, ex3);
  float sr[4] = {ex0, ex1, ex2, ex3};
#pragma unroll
  for (int r = 0; r < 4; ++r) {
    float v = sr[r];
    v += __shfl_xor(v, 1, 64);
    v += __shfl_xor(v, 2, 64);
    v += __shfl_xor(v, 4, 64);
    v += __shfl_xor(v, 8, 64);
    if ((lane & 15) == 0) atomicAdd(S + (size_t)(quad * 4 + r) * 16, v);
  }
}

// part[nb][h][m] = sum_{n in 256-row chunk} e[n,h]*value[n,m]
// e chunk staged in LDS; value loads batched 8 deep; cross-wave tree-reduce.
__global__ __launch_bounds__(256, 2) void k_pv(const float* __restrict__ value,
                                               const float* __restrict__ e,
                                               float* __restrict__ part) {
  const int nb = blockIdx.x >> 2;        // 0..63
  const int mc = blockIdx.x & 3;
  const int t = threadIdx.x;
  const int lane = t & 63;
  const int wy = t >> 6;                 // 0..3 row stripe (64 rows each)
  const int col = mc * 256 + lane * 4;
  const int n0 = nb * 256;
  __shared__ float el[256 * 16];         // 16 KB
  __shared__ float4 red[2][16][64];      // 32 KB
  {
    const float4* eg = (const float4*)(e + (size_t)n0 * 16);  // 1024 float4
    float4* es = (float4*)el;
#pragma unroll
    for (int k = 0; k < 4; ++k) es[t + k * 256] = eg[t + k * 256];
  }
  __syncthreads();
  float4 acc[16];
#pragma unroll
  for (int h = 0; h < 16; ++h) acc[h] = make_float4(0.f, 0.f, 0.f, 0.f);
  const float* vp = value + (size_t)(n0 + wy * 64) * DM + col;
  const float* ep = &el[wy * 64 * 16];
#pragma unroll 1
  for (int rb = 0; rb < 8; ++rb) {       // 8 batches of 8 rows
    float4 v[8];
#pragma unroll
    for (int i = 0; i < 8; ++i) v[i] = *(const float4*)(vp + (size_t)(rb * 8 + i) * DM);
#pragma unroll
    for (int i = 0; i < 8; ++i) {
      const float4* er4 = (const float4*)(ep + (rb * 8 + i) * 16);
      float4 e0 = er4[0], e1 = er4[1], e2 = er4[2], e3 = er4[3];
      float4 vv = v[i];
#define FMA4H(H, P) { acc[H].x = fmaf(P, vv.x, acc[H].x); acc[H].y = fmaf(P, vv.y, acc[H].y); \
                      acc[H].z = fmaf(P, vv.z, acc[H].z); acc[H].w = fmaf(P, vv.w, acc[H].w); }
      FMA4H(0,  e0.x) FMA4H(1,  e0.y) FMA4H(2,  e0.z) FMA4H(3,  e0.w)
      FMA4H(4,  e1.x) FMA4H(5,  e1.y) FMA4H(6,  e1.z) FMA4H(7,  e1.w)
      FMA4H(8,  e2.x) FMA4H(9,  e2.y) FMA4H(10, e2.z) FMA4H(11, e2.w)
      FMA4H(12, e3.x) FMA4H(13, e3.y) FMA4H(14, e3.z) FMA4H(15, e3.w)
#undef FMA4H
    }
  }
  if (wy >= 2) {
#pragma unroll
    for (int h = 0; h < 16; ++h) red[wy - 2][h][lane] = acc[h];
  }
  __syncthreads();
  if (wy < 2) {
#pragma unroll
    for (int h = 0; h < 16; ++h) {
      float4 o = red[wy][h][lane];
      acc[h].x += o.x; acc[h].y += o.y; acc[h].z += o.z; acc[h].w += o.w;
    }
  }
  __syncthreads();
  if (wy == 1) {
#pragma unroll
    for (int h = 0; h < 16; ++h) red[0][h][lane] = acc[h];
  }
  __syncthreads();
  if (wy == 0) {
    float* pp = part + (size_t)nb * (16 * DM) + col;
#pragma unroll
    for (int h = 0; h < 16; ++h) {
      float4 o = red[0][h][lane];
      acc[h].x += o.x; acc[h].y += o.y; acc[h].z += o.z; acc[h].w += o.w;
      *(float4*)(pp + (size_t)h * DM) = acc[h];
    }
  }
}

// w[o] = sum_nb part[nb][o] — 4 threads per output, 16 chunks each
__global__ __launch_bounds__(256) void k_wred(const float* __restrict__ part,
                                              float* __restrict__ w) {
  const int gid = blockIdx.x * 256 + threadIdx.x;  // 0..65535
  const int o = gid >> 2;
  const int q = gid & 3;
  float s = 0.f;
#pragma unroll 1
  for (int ib = 0; ib < 2; ++ib) {
    float x[8];
#pragma unroll
    for (int j = 0; j < 8; ++j) x[j] = part[(size_t)(q * 16 + ib * 8 + j) * 16384 + o];
#pragma unroll
    for (int j = 0; j < 8; ++j) s += x[j];
  }
  s += __shfl_xor(s, 1, 64);
  s += __shfl_xor(s, 2, 64);
  if (q == 0) w[o] = s;
}

// x[r] = dot(Wv[r,:], w[h,:]) / S[h] + bv[r],  h = r>>6 — wave per row
__global__ __launch_bounds__(256) void k_xproj(const float* __restrict__ Wv,
                                               const float* __restrict__ w,
                                               const float* __restrict__ bv,
                                               const float* __restrict__ S,
                                               float* __restrict__ x) {
  const int wave = (blockIdx.x * 256 + threadIdx.x) >> 6;
  const int lane = threadIdx.x & 63;
  const int h = wave >> 6;
  const float* vec = w + (size_t)h * DM;
  const float* row = Wv + (size_t)wave * DM + 4 * lane;
  float s = 0.f;
#pragma unroll
  for (int j = 0; j < 4; ++j) {
    float4 a = *(const float4*)(row + j * 256);
    float4 x4 = *(const float4*)(vec + j * 256 + 4 * lane);
    s += a.x * x4.x + a.y * x4.y + a.z * x4.z + a.w * x4.w;
  }
#pragma unroll
  for (int off = 32; off; off >>= 1) s += __shfl_xor(s, off, 64);
  if (lane == 0) x[wave] = s / S[(size_t)h * 16] + bv[wave];
}

extern "C" void kernel_launch(void* const* d_in, const int* in_sizes, int n_in,
                              void* d_out, int out_size, void* d_ws, size_t ws_size,
                              hipStream_t stream) {
  const float* query = (const float*)d_in[0];
  const float* key   = (const float*)d_in[1];
  const float* value = (const float*)d_in[2];
  const float* Wq    = (const float*)d_in[3];
  const float* bq    = (const float*)d_in[4];
  const float* Wk    = (const float*)d_in[5];
  const float* bk    = (const float*)d_in[6];
  const float* Wv    = (const float*)d_in[7];
  const float* bv    = (const float*)d_in[8];
  const float* Wo    = (const float*)d_in[9];
  const float* bo    = (const float*)d_in[10];
  float* out = (float*)d_out;
  float* ws  = (float*)d_ws;
  short* Ah  = (short*)(ws + OFF_AH);
  short* Al  = (short*)(ws + OFF_AL);

  k_qck    <<<64,  256, 0, stream>>>(Wq, bq, query, Wk, bk, Ah, Al, ws + OFF_D0, ws + OFF_S);
  k_scores <<<256, 256, 0, stream>>>(key, Ah, Al, ws + OFF_D0, ws + OFF_E, ws + OFF_S);
  k_pv     <<<256, 256, 0, stream>>>(value, ws + OFF_E, ws + OFF_PART);
  k_wred   <<<256, 256, 0, stream>>>(ws + OFF_PART, ws + OFF_W);
  k_xproj  <<<256, 256, 0, stream>>>(Wv, ws + OFF_W, bv, ws + OFF_S, ws + OFF_X);
  k_rowdot <<<256, 256, 0, stream>>>(Wo, ws + OFF_X, bo, out);
}

// Round 7
// 238.933 us; speedup vs baseline: 1.0079x; 1.0079x over previous
//
#include <hip/hip_runtime.h>

#define DM 1024
#define NW 16384

typedef __attribute__((ext_vector_type(8))) short short8;
typedef __attribute__((ext_vector_type(4))) float f32x4;

// ws layout (float offsets) — total 2396160 floats (~9.6 MB, proven fit)
#define OFF_AH   1024       // A-frag hi: 16384 shorts = 8192 floats
#define OFF_AL   9216       // A-frag lo: 16384 shorts
#define OFF_D0   17408      // 16
#define OFF_S    17424      // 16 heads, stride 16 floats = 256
#define OFF_X    17696      // 1024
#define OFF_W    18720      // 16*1024
#define OFF_E    36864      // e[NW][16] = 262144
#define OFF_PART 299008     // partials [64][16][1024] = 1048576

// fp32 -> bf16 round-to-nearest-even (returns bits)
__device__ __forceinline__ unsigned short f2bf(float f) {
  unsigned int u = __float_as_uint(f);
  return (unsigned short)((u + 0x7fffu + ((u >> 16) & 1u)) >> 16);
}

// out[r] = dot(W[r,:], v) + b[r]   — one wave per row, 1024 waves
__global__ __launch_bounds__(256) void k_rowdot(const float* __restrict__ W,
                                                const float* __restrict__ v,
                                                const float* __restrict__ b,
                                                float* __restrict__ out) {
  const int wave = (blockIdx.x * 256 + threadIdx.x) >> 6;
  const int lane = threadIdx.x & 63;
  const float* row = W + (size_t)wave * DM + 4 * lane;
  float s = 0.f;
#pragma unroll
  for (int j = 0; j < 4; ++j) {
    float4 a = *(const float4*)(row + j * 256);
    float4 x = *(const float4*)(v + j * 256 + 4 * lane);
    s += a.x * x.x + a.y * x.y + a.z * x.z + a.w * x.w;
  }
#pragma unroll
  for (int off = 32; off; off >>= 1) s += __shfl_xor(s, off, 64);
  if (lane == 0) out[wave] = s + b[wave];
}

// Fused: q_h = query@Wq_h^T + bq (LDS), then c[h,m] = q_h · Wk[h*64+:,m],
// emitted directly as MFMA A-fragments (bf16 hi+lo). d0[h] = q_h·bk_h. Zeroes S.
__global__ __launch_bounds__(256) void k_qck(const float* __restrict__ Wq,
                                             const float* __restrict__ bq,
                                             const float* __restrict__ query,
                                             const float* __restrict__ Wk,
                                             const float* __restrict__ bk,
                                             short* __restrict__ Ah,
                                             short* __restrict__ Al,
                                             float* __restrict__ d0,
                                             float* __restrict__ S) {
  const int h = blockIdx.x >> 2;
  const int mc = blockIdx.x & 3;
  const int t = threadIdx.x;
  const int lane = t & 63;
  const int wv = t >> 6;
  __shared__ float qh[64];
  if (blockIdx.x == 0 && t < 16) S[t * 16] = 0.f;
  float4 qv[4];
#pragma unroll
  for (int j = 0; j < 4; ++j) qv[j] = *(const float4*)(query + j * 256 + 4 * lane);
#pragma unroll 1
  for (int i = 0; i < 16; i += 2) {
    const int d0i = 4 * i + wv;
    const int d1i = 4 * (i + 1) + wv;
    const float* r0 = Wq + (size_t)(h * 64 + d0i) * DM + 4 * lane;
    const float* r1 = Wq + (size_t)(h * 64 + d1i) * DM + 4 * lane;
    float4 a0[4], a1[4];
#pragma unroll
    for (int j = 0; j < 4; ++j) { a0[j] = *(const float4*)(r0 + j * 256);
                                  a1[j] = *(const float4*)(r1 + j * 256); }
    float s0 = 0.f, s1 = 0.f;
#pragma unroll
    for (int j = 0; j < 4; ++j) {
      s0 += a0[j].x * qv[j].x + a0[j].y * qv[j].y + a0[j].z * qv[j].z + a0[j].w * qv[j].w;
      s1 += a1[j].x * qv[j].x + a1[j].y * qv[j].y + a1[j].z * qv[j].z + a1[j].w * qv[j].w;
    }
#pragma unroll
    for (int off = 32; off; off >>= 1) { s0 += __shfl_xor(s0, off, 64);
                                         s1 += __shfl_xor(s1, off, 64); }
    if (lane == 0) { qh[d0i] = s0 + bq[h * 64 + d0i];
                     qh[d1i] = s1 + bq[h * 64 + d1i]; }
  }
  __syncthreads();
  const int m = mc * 256 + t;
  const float* Wp = Wk + (size_t)(h * 64) * DM + m;
  float s = 0.f;
#pragma unroll 1
  for (int db = 0; db < 8; ++db) {
    float wv8[8];
#pragma unroll
    for (int j = 0; j < 8; ++j) wv8[j] = Wp[(size_t)(db * 8 + j) * DM];
#pragma unroll
    for (int j = 0; j < 8; ++j) s = fmaf(qh[db * 8 + j], wv8[j], s);
  }
  unsigned short hu = f2bf(s);
  float hf = __uint_as_float(((unsigned int)hu) << 16);
  unsigned short lu = f2bf(s - hf);
  const int kb = m >> 5, q = (m >> 3) & 3, j = m & 7;
  const int idx = (kb * 64 + q * 16 + h) * 8 + j;
  Ah[idx] = (short)hu;
  Al[idx] = (short)lu;
  if (mc == 0 && t == 0) {
    float tt = 0.f;
    for (int d = 0; d < 64; ++d) tt += qh[d] * bk[h * 64 + d];
    d0[h] = tt;
  }
}

// MFMA scores, K-split 8: block(512) = 8 waves = one 16-row tile; wave wv does
// kb = wv*4..wv*4+3 (K=128) with 3 hi/lo MFMAs per kb; partials combined in
// LDS; wave 0: +d0, exp, store e, atomicAdd S. A-frags read from global (L2).
__global__ __launch_bounds__(512) void k_scores(const float* __restrict__ key,
                                                const short* __restrict__ AhG,
                                                const short* __restrict__ AlG,
                                                const float* __restrict__ d0,
                                                float* __restrict__ e,
                                                float* __restrict__ S) {
  const int t = threadIdx.x;
  const int lane = t & 63;
  const int wv = t >> 6;                  // 0..7 — K-split index
  const int tile = blockIdx.x;            // 0..1023
  const int n = tile * 16 + (lane & 15);
  const int quad = lane >> 4;
  const int kb0 = wv * 4;
  const float* base = key + (size_t)n * DM + quad * 8;
  const short8* A8h = (const short8*)AhG;
  const short8* A8l = (const short8*)AlG;

  // issue all 16 loads (8 key float4 + 8 A short8) up front
  short8 ah[4], al[4];
  float4 f0[4], f1[4];
#pragma unroll
  for (int i = 0; i < 4; ++i) {
    ah[i] = A8h[(kb0 + i) * 64 + lane];
    al[i] = A8l[(kb0 + i) * 64 + lane];
    f0[i] = *(const float4*)(base + (kb0 + i) * 32);
    f1[i] = *(const float4*)(base + (kb0 + i) * 32 + 4);
  }
  f32x4 acc = {0.f, 0.f, 0.f, 0.f};
#pragma unroll
  for (int i = 0; i < 4; ++i) {
    float ff[8] = {f0[i].x, f0[i].y, f0[i].z, f0[i].w,
                   f1[i].x, f1[i].y, f1[i].z, f1[i].w};
    short8 bh, bl;
#pragma unroll
    for (int j = 0; j < 8; ++j) {
      unsigned short hu = f2bf(ff[j]);
      bh[j] = (short)hu;
      float hf = __uint_as_float(((unsigned int)hu) << 16);
      bl[j] = (short)f2bf(ff[j] - hf);
    }
    acc = __builtin_amdgcn_mfma_f32_16x16x32_bf16(ah[i], bh, acc, 0, 0, 0);
    acc = __builtin_amdgcn_mfma_f32_16x16x32_bf16(ah[i], bl, acc, 0, 0, 0);
    acc = __builtin_amdgcn_mfma_f32_16x16x32_bf16(al[i], bh, acc, 0, 0, 0);
  }
  __shared__ float4 red[8][64];           // 8 KB
  red[wv][lane] = make_float4(acc[0], acc[1], acc[2], acc[3]);
  __syncthreads();
  if (wv == 0) {
    float4 a = red[0][lane];
#pragma unroll
    for (int w = 1; w < 8; ++w) {
      float4 o = red[w][lane];
      a.x += o.x; a.y += o.y; a.z += o.z; a.w += o.w;
    }
    const float4 dv = *(const float4*)(d0 + quad * 4);
    float ex0 = __expf(a.x + dv.x);
    float ex1 = __expf(a.y + dv.y);
    float ex2 = __expf(a.z + dv.z);
    float ex3 = __expf(a.w + dv.w);
    *(float4*)(e + (size_t)n * 16 + quad * 4) = make_float4(ex0, ex1, ex2, ex3);
    float sr[4] = {ex0, ex1, ex2, ex3};
#pragma unroll
    for (int r = 0; r < 4; ++r) {
      float v = sr[r];
      v += __shfl_xor(v, 1, 64);
      v += __shfl_xor(v, 2, 64);
      v += __shfl_xor(v, 4, 64);
      v += __shfl_xor(v, 8, 64);
      if ((lane & 15) == 0) atomicAdd(S + (size_t)(quad * 4 + r) * 16, v);
    }
  }
}

// part[nb][h][m] = sum_{n in 256-row chunk} e[n,h]*value[n,m]
__global__ __launch_bounds__(256, 2) void k_pv(const float* __restrict__ value,
                                               const float* __restrict__ e,
                                               float* __restrict__ part) {
  const int nb = blockIdx.x >> 2;        // 0..63
  const int mc = blockIdx.x & 3;
  const int t = threadIdx.x;
  const int lane = t & 63;
  const int wy = t >> 6;                 // 0..3 row stripe (64 rows each)
  const int col = mc * 256 + lane * 4;
  const int n0 = nb * 256;
  __shared__ float el[256 * 16];         // 16 KB
  __shared__ float4 red[2][16][64];      // 32 KB
  {
    const float4* eg = (const float4*)(e + (size_t)n0 * 16);
    float4* es = (float4*)el;
#pragma unroll
    for (int k = 0; k < 4; ++k) es[t + k * 256] = eg[t + k * 256];
  }
  __syncthreads();
  float4 acc[16];
#pragma unroll
  for (int h = 0; h < 16; ++h) acc[h] = make_float4(0.f, 0.f, 0.f, 0.f);
  const float* vp = value + (size_t)(n0 + wy * 64) * DM + col;
  const float* ep = &el[wy * 64 * 16];
#pragma unroll 1
  for (int rb = 0; rb < 8; ++rb) {
    float4 v[8];
#pragma unroll
    for (int i = 0; i < 8; ++i) v[i] = *(const float4*)(vp + (size_t)(rb * 8 + i) * DM);
#pragma unroll
    for (int i = 0; i < 8; ++i) {
      const float4* er4 = (const float4*)(ep + (rb * 8 + i) * 16);
      float4 e0 = er4[0], e1 = er4[1], e2 = er4[2], e3 = er4[3];
      float4 vv = v[i];
#define FMA4H(H, P) { acc[H].x = fmaf(P, vv.x, acc[H].x); acc[H].y = fmaf(P, vv.y, acc[H].y); \
                      acc[H].z = fmaf(P, vv.z, acc[H].z); acc[H].w = fmaf(P, vv.w, acc[H].w); }
      FMA4H(0,  e0.x) FMA4H(1,  e0.y) FMA4H(2,  e0.z) FMA4H(3,  e0.w)
      FMA4H(4,  e1.x) FMA4H(5,  e1.y) FMA4H(6,  e1.z) FMA4H(7,  e1.w)
      FMA4H(8,  e2.x) FMA4H(9,  e2.y) FMA4H(10, e2.z) FMA4H(11, e2.w)
      FMA4H(12, e3.x) FMA4H(13, e3.y) FMA4H(14, e3.z) FMA4H(15, e3.w)
#undef FMA4H
    }
  }
  if (wy >= 2) {
#pragma unroll
    for (int h = 0; h < 16; ++h) red[wy - 2][h][lane] = acc[h];
  }
  __syncthreads();
  if (wy < 2) {
#pragma unroll
    for (int h = 0; h < 16; ++h) {
      float4 o = red[wy][h][lane];
      acc[h].x += o.x; acc[h].y += o.y; acc[h].z += o.z; acc[h].w += o.w;
    }
  }
  __syncthreads();
  if (wy == 1) {
#pragma unroll
    for (int h = 0; h < 16; ++h) red[0][h][lane] = acc[h];
  }
  __syncthreads();
  if (wy == 0) {
    float* pp = part + (size_t)nb * (16 * DM) + col;
#pragma unroll
    for (int h = 0; h < 16; ++h) {
      float4 o = red[0][h][lane];
      acc[h].x += o.x; acc[h].y += o.y; acc[h].z += o.z; acc[h].w += o.w;
      *(float4*)(pp + (size_t)h * DM) = acc[h];
    }
  }
}

// w[o] = sum_nb part[nb][o] — 4 threads per output, 16 chunks each
__global__ __launch_bounds__(256) void k_wred(const float* __restrict__ part,
                                              float* __restrict__ w) {
  const int gid = blockIdx.x * 256 + threadIdx.x;
  const int o = gid >> 2;
  const int q = gid & 3;
  float s = 0.f;
#pragma unroll 1
  for (int ib = 0; ib < 2; ++ib) {
    float x[8];
#pragma unroll
    for (int j = 0; j < 8; ++j) x[j] = part[(size_t)(q * 16 + ib * 8 + j) * 16384 + o];
#pragma unroll
    for (int j = 0; j < 8; ++j) s += x[j];
  }
  s += __shfl_xor(s, 1, 64);
  s += __shfl_xor(s, 2, 64);
  if (q == 0) w[o] = s;
}

// x[r] = dot(Wv[r,:], w[h,:]) / S[h] + bv[r],  h = r>>6 — wave per row
__global__ __launch_bounds__(256) void k_xproj(const float* __restrict__ Wv,
                                               const float* __restrict__ w,
                                               const float* __restrict__ bv,
                                               const float* __restrict__ S,
                                               float* __restrict__ x) {
  const int wave = (blockIdx.x * 256 + threadIdx.x) >> 6;
  const int lane = threadIdx.x & 63;
  const int h = wave >> 6;
  const float* vec = w + (size_t)h * DM;
  const float* row = Wv + (size_t)wave * DM + 4 * lane;
  float s = 0.f;
#pragma unroll
  for (int j = 0; j < 4; ++j) {
    float4 a = *(const float4*)(row + j * 256);
    float4 x4 = *(const float4*)(vec + j * 256 + 4 * lane);
    s += a.x * x4.x + a.y * x4.y + a.z * x4.z + a.w * x4.w;
  }
#pragma unroll
  for (int off = 32; off; off >>= 1) s += __shfl_xor(s, off, 64);
  if (lane == 0) x[wave] = s / S[(size_t)h * 16] + bv[wave];
}

extern "C" void kernel_launch(void* const* d_in, const int* in_sizes, int n_in,
                              void* d_out, int out_size, void* d_ws, size_t ws_size,
                              hipStream_t stream) {
  const float* query = (const float*)d_in[0];
  const float* key   = (const float*)d_in[1];
  const float* value = (const float*)d_in[2];
  const float* Wq    = (const float*)d_in[3];
  const float* bq    = (const float*)d_in[4];
  const float* Wk    = (const float*)d_in[5];
  const float* bk    = (const float*)d_in[6];
  const float* Wv    = (const float*)d_in[7];
  const float* bv    = (const float*)d_in[8];
  const float* Wo    = (const float*)d_in[9];
  const float* bo    = (const float*)d_in[10];
  float* out = (float*)d_out;
  float* ws  = (float*)d_ws;
  short* Ah  = (short*)(ws + OFF_AH);
  short* Al  = (short*)(ws + OFF_AL);

  k_qck    <<<64,  256, 0, stream>>>(Wq, bq, query, Wk, bk, Ah, Al, ws + OFF_D0, ws + OFF_S);
  k_scores <<<1024,512, 0, stream>>>(key, Ah, Al, ws + OFF_D0, ws + OFF_E, ws + OFF_S);
  k_pv     <<<256, 256, 0, stream>>>(value, ws + OFF_E, ws + OFF_PART);
  k_wred   <<<256, 256, 0, stream>>>(ws + OFF_PART, ws + OFF_W);
  k_xproj  <<<256, 256, 0, stream>>>(Wv, ws + OFF_W, bv, ws + OFF_S, ws + OFF_X);
  k_rowdot <<<256, 256, 0, stream>>>(Wo, ws + OFF_X, bo, out);
}